// Round 7
// baseline (265.984 us; speedup 1.0000x reference)
//
#include <hip/hip_runtime.h>

// Problem constants
#define BB 2
#define NN 4
#define DD 48
#define HH 28
#define WW 60
#define CC 64
#define NXg 192
#define NYg 192
#define NZg 1
#define DOWNS 8

constexpr int PTS    = BB * NN * DD * HH * WW;       // 645120 points
constexpr int NMAT   = BB * NN;                      // 8 camera matrices
constexpr int CH_STRIDE = NYg * NXg;                 // 36864 floats per channel plane

// ---------------------------------------------------------------------------
// Kernel P: tiny prep — per-(b,n) combine = R @ K^-1 and trans, in f64
// (hoisted out of the per-point kernel: it was computed 645120x redundantly).
// Also zeroes the work-item cursor.
// ---------------------------------------------------------------------------
__global__ void prep_kernel(const float* __restrict__ intr,
                            const float* __restrict__ pose,
                            double* __restrict__ mats,
                            int* __restrict__ n_items) {
    int t = threadIdx.x;
    if (t == 0) *n_items = 0;
    if (t >= NMAT) return;

    const float* K  = intr + (size_t)t * 9;
    const float* Pm = pose + (size_t)t * 16;

    double k00 = K[0], k01 = K[1], k02 = K[2];
    double k10 = K[3], k11 = K[4], k12 = K[5];
    double k20 = K[6], k21 = K[7], k22 = K[8];

    double det = k00 * (k11 * k22 - k12 * k21)
               - k01 * (k10 * k22 - k12 * k20)
               + k02 * (k10 * k21 - k11 * k20);
    double id = 1.0 / det;
    double i00 = (k11 * k22 - k12 * k21) * id;
    double i01 = (k02 * k21 - k01 * k22) * id;
    double i02 = (k01 * k12 - k02 * k11) * id;
    double i10 = (k12 * k20 - k10 * k22) * id;
    double i11 = (k00 * k22 - k02 * k20) * id;
    double i12 = (k02 * k10 - k00 * k12) * id;
    double i20 = (k10 * k21 - k11 * k20) * id;
    double i21 = (k01 * k20 - k00 * k21) * id;
    double i22 = (k00 * k11 - k01 * k10) * id;

    double r00 = Pm[0],  r01 = Pm[1],  r02 = Pm[2],  tx = Pm[3];
    double r10 = Pm[4],  r11 = Pm[5],  r12 = Pm[6],  ty = Pm[7];
    double r20 = Pm[8],  r21 = Pm[9],  r22 = Pm[10], tz = Pm[11];

    double* M = mats + t * 12;
    M[0] = r00 * i00 + r01 * i10 + r02 * i20;
    M[1] = r00 * i01 + r01 * i11 + r02 * i21;
    M[2] = r00 * i02 + r01 * i12 + r02 * i22;
    M[3] = r10 * i00 + r11 * i10 + r12 * i20;
    M[4] = r10 * i01 + r11 * i11 + r12 * i21;
    M[5] = r10 * i02 + r11 * i12 + r12 * i22;
    M[6] = r20 * i00 + r21 * i10 + r22 * i20;
    M[7] = r20 * i01 + r21 * i11 + r22 * i21;
    M[8] = r20 * i02 + r21 * i12 + r22 * i22;
    M[9] = tx; M[10] = ty; M[11] = tz;
}

// ---------------------------------------------------------------------------
// Kernel A: geometry + block-local grouping + work-item emission.
// Thread decode is h-INNERMOST (b,n,d,w,h): a block's 256 points are ~9
// (d,w)-columns whose 28 h-points nearly all share one BEV cell -> ~9 distinct
// cells/block. LDS hash groups points by cell; an LDS scan assigns each slot
// a contiguous range of the block's private pool window [blockIdx*256, +256);
// ONE global atomic per block bump-allocates work items (cell<<8|len-1, base).
// Replaces histogram + 2 scan kernels + fill kernel + counts memset.
// ---------------------------------------------------------------------------
__global__ void __launch_bounds__(256)
geom_emit_kernel(const double* __restrict__ mats,
                 int2* __restrict__ work,
                 int* __restrict__ pool,
                 int* __restrict__ n_items) {
    __shared__ int hkey[512];
    __shared__ int hval[512];
    __shared__ int hbase[512];
    __shared__ long long wsum[4];
    __shared__ int itemBase_sh;

    int tid = threadIdx.x, lane = tid & 63, wv = tid >> 6;
    hkey[tid] = -1;       hval[tid] = 0;
    hkey[tid + 256] = -1; hval[tid + 256] = 0;
    __syncthreads();

    // transposed decode: h innermost
    int q = blockIdx.x * 256 + tid;
    int h = q % HH;
    int t = q / HH;
    int w = t % WW; t /= WW;
    int d = t % DD; t /= DD;
    int bn = t;                                   // b*NN + n
    // x-row index in original (b,n,d,h,w) order:
    int p_x = ((bn * DD + d) * HH + h) * WW + w;

    const double* M = mats + bn * 12;
    double u   = (double)w * ((double)(WW * DOWNS - 1) / (double)(WW - 1));
    double v   = (double)h * ((double)(HH * DOWNS - 1) / (double)(HH - 1));
    double dep = 2.0 + (double)d;
    double px = u * dep, py = v * dep, pz = dep;

    double gxf = (M[0] * px + M[1] * py + M[2] * pz + M[9])  * 4.0 + 96.0;
    double gyf = (M[3] * px + M[4] * py + M[5] * pz + M[10]) * 4.0 + 96.0;
    double gzf = ((M[6] * px + M[7] * py + M[8] * pz + M[11]) + 10.0) / 20.0;

    int gx = (int)gxf;
    int gy = (int)gyf;
    int gz = (int)gzf;
    int b  = bn >> 2;   // bn / NN

    bool kept = (gx >= 0) & (gx < NXg) & (gy >= 0) & (gy < NYg) &
                (gz >= 0) & (gz < NZg);
    int cell = kept ? (((b * NZg + gz) * NYg + gy) * NXg + gx) : -1;

    // ---- LDS hash insert ----
    int slot = -1, lrank = 0;
    if (cell >= 0) {
        unsigned hsh = ((unsigned)cell * 2654435761u) >> 21;
        slot = (int)(hsh & 511u);
        while (true) {
            int prev = atomicCAS(&hkey[slot], -1, cell);
            if (prev == -1 || prev == cell) break;
            slot = (slot + 1) & 511;
        }
        lrank = atomicAdd(&hval[slot], 1);
    }
    __syncthreads();

    // ---- packed scan over 512 slots (2 per thread): pool prefix | occ prefix
    int s0 = tid, s1 = tid + 256;
    int c0 = hval[s0], c1 = hval[s1];
    int o0 = (hkey[s0] >= 0) ? 1 : 0;
    int o1 = (hkey[s1] >= 0) ? 1 : 0;
    long long pk = ((long long)(c0 + c1) << 20) | (long long)(o0 + o1);
    long long incl = pk;
    #pragma unroll
    for (int o = 1; o < 64; o <<= 1) {
        long long tt = __shfl_up(incl, o, 64);
        if (lane >= o) incl += tt;
    }
    if (lane == 63) wsum[wv] = incl;
    __syncthreads();
    if (tid == 0) {
        long long run = 0;
        #pragma unroll
        for (int k = 0; k < 4; ++k) { long long tt = wsum[k]; wsum[k] = run; run += tt; }
        int totOcc = (int)(run & 0xFFFFF);
        itemBase_sh = totOcc ? atomicAdd(n_items, totOcc) : 0;
    }
    __syncthreads();
    long long excl = wsum[wv] + incl - pk;
    int poolPfx = (int)(excl >> 20);
    int occPfx  = (int)(excl & 0xFFFFF);

    int blockPool = blockIdx.x * 256;
    if (o0) {
        int base = blockPool + poolPfx;
        hbase[s0] = base;
        work[itemBase_sh + occPfx] = make_int2((hkey[s0] << 8) | (c0 - 1), base);
    }
    if (o1) {
        int base = blockPool + poolPfx + c0;
        hbase[s1] = base;
        work[itemBase_sh + occPfx + o0] = make_int2((hkey[s1] << 8) | (c1 - 1), base);
    }
    __syncthreads();
    if (cell >= 0) pool[hbase[slot] + lrank] = p_x;
}

// ---------------------------------------------------------------------------
// Kernel B: one wave per work item (cell, base, len<=256). Row ids arrive in
// coalesced 64-wide pool loads; __shfl broadcast drives 8-deep independent
// x-row loads (lane = channel). One atomicAdd per lane per item into out
// (contention = items per cell, ~4-30).
// ---------------------------------------------------------------------------
__global__ void __launch_bounds__(256)
gather_kernel(const float* __restrict__ x,
              const int2* __restrict__ work,
              const int* __restrict__ pool,
              const int* __restrict__ n_items,
              float* __restrict__ out) {
    int lane = threadIdx.x & 63;
    int gw   = blockIdx.x * (blockDim.x >> 6) + (threadIdx.x >> 6);
    int stride = gridDim.x * (blockDim.x >> 6);
    int n = *n_items;

    for (int j = gw; j < n; j += stride) {
        int2 e   = work[j];
        int cell = e.x >> 8;
        int m    = (e.x & 255) + 1;
        int base = e.y;

        float a0 = 0.f, a1 = 0.f, a2 = 0.f, a3 = 0.f;
        float a4 = 0.f, a5 = 0.f, a6 = 0.f, a7 = 0.f;
        for (int i0 = 0; i0 < m; i0 += 64) {
            int mm = m - i0; if (mm > 64) mm = 64;
            int bid = (lane < mm) ? pool[base + i0 + lane] : 0;
            int i = 0;
            for (; i + 8 <= mm; i += 8) {
                int p0 = __shfl(bid, i + 0);
                int p1 = __shfl(bid, i + 1);
                int p2 = __shfl(bid, i + 2);
                int p3 = __shfl(bid, i + 3);
                int p4 = __shfl(bid, i + 4);
                int p5 = __shfl(bid, i + 5);
                int p6 = __shfl(bid, i + 6);
                int p7 = __shfl(bid, i + 7);
                a0 += x[(size_t)p0 * CC + lane];
                a1 += x[(size_t)p1 * CC + lane];
                a2 += x[(size_t)p2 * CC + lane];
                a3 += x[(size_t)p3 * CC + lane];
                a4 += x[(size_t)p4 * CC + lane];
                a5 += x[(size_t)p5 * CC + lane];
                a6 += x[(size_t)p6 * CC + lane];
                a7 += x[(size_t)p7 * CC + lane];
            }
            for (; i < mm; ++i) {
                int p0 = __shfl(bid, i);
                a0 += x[(size_t)p0 * CC + lane];
            }
        }
        float s = ((a0 + a1) + (a2 + a3)) + ((a4 + a5) + (a6 + a7));

        int yx = cell % (NYg * NXg);
        int bz = cell / (NYg * NXg);
        atomicAdd(&out[((size_t)bz * CC + lane) * CH_STRIDE + yx], s);
    }
}

// ---------------------------------------------------------------------------
extern "C" void kernel_launch(void* const* d_in, const int* in_sizes, int n_in,
                              void* d_out, int out_size, void* d_ws, size_t ws_size,
                              hipStream_t stream) {
    const float* x    = (const float*)d_in[0];
    const float* intr = (const float*)d_in[1];
    const float* pose = (const float*)d_in[2];
    float* out = (float*)d_out;

    double* mats = (double*)d_ws;                  // NMAT*12 doubles (768 B)
    int* n_items = (int*)(mats + NMAT * 12);       // 1 int (+1 pad)
    int2* work   = (int2*)(n_items + 2);           // up to PTS items (5.2 MB)
    int* pool    = (int*)(work + PTS);             // PTS ints (2.6 MB)
    // total ws use ~= 7.8 MB

    hipMemsetAsync(out, 0, (size_t)out_size * sizeof(float), stream);
    prep_kernel<<<1, 64, 0, stream>>>(intr, pose, mats, n_items);
    geom_emit_kernel<<<PTS / 256, 256, 0, stream>>>(mats, work, pool, n_items);
    gather_kernel<<<1024, 256, 0, stream>>>(x, work, pool, n_items, out);
}